// Round 10
// baseline (24.417 us; speedup 1.0000x reference)
//
#include <hip/hip_runtime.h>

// Problem constants (fixed by the reference)
#define C8     8      // feat channels
#define KOBJ   32     // objects per image
#define BIMG   8      // batch
#define WW     128
#define HWPIX  16384  // H*W
#define CWN    169    // conv params per object
#define PIX    8      // contiguous pixels per thread
#define GRIDX  8      // tiles per (b,k)
#define NBLK   (BIMG * KOBJ * GRIDX)    // 2048 blocks
#define WSLOTS_PER_B (KOBJ * GRIDX * 4) // 1024 wave-slots per image

// Weight vector layout (identity slots i = 0..168):
//  i<80   : l1w[o][c], o=i/10, c=i%10 (c 0..7 seg, 8=wx, 9=wy)
//  80..87 : l1b
//  88..151: l2w[o][c], u=i-88, o=u/8, c=u%8
//  152..159: l2b
//  160..167: l3w
//  168    : l3b

__global__ __launch_bounds__(256) void mask_head_kernel(
    const float* __restrict__ seg_feat,    // [B,8,H,W]
    const float* __restrict__ conv_weight, // [B,169,H,W]
    const int* __restrict__ mask,          // [B,K]
    const long long* __restrict__ ind,     // [B,K]
    const float* __restrict__ target,      // [B,K,H,W]
    float* __restrict__ partial)           // [NBLK*4][3] per-wave slots
{
    const int tile = blockIdx.x;
    const int k    = blockIdx.y;
    const int b    = blockIdx.z;
    const int t    = threadIdx.x;
    const int lane = t & 63;
    const int wid  = t >> 6;
    const int pair = b * KOBJ + k;
    const int slot = pair * GRIDX + tile;
    float* wout = partial + (slot * 4 + wid) * 3;

    // Parallel independent uniform loads (s_load): mask and ind together.
    const int       mval  = mask[pair];
    const long long idxll = ind[pair];
    if (mval == 0) {                 // masked: each wave zeroes its own slot
        if (lane == 0) { wout[0] = 0.f; wout[1] = 0.f; wout[2] = 0.f; }
        return;
    }
    const int idx = (int)idxll;

    // Per-wave private weight copy -> NO __syncthreads anywhere.
    __shared__ float wds[4][CWN + 7];
    float* wp = wds[wid];

    // Per-lane gather: 3 scattered loads per lane cover all 169 weights.
    const float* cwb = conv_weight + b * CWN * HWPIX + idx;
    const float g0 = cwb[lane * HWPIX];
    const float g1 = cwb[(lane + 64) * HWPIX];
    float g2 = 0.f;
    if (lane < CWN - 128) g2 = cwb[(lane + 128) * HWPIX];

    // Prefetch target + first-half seg while the gather is in flight.
    const float* seg = seg_feat + b * C8 * HWPIX;
    const float* tgt = target + pair * HWPIX;
    const int p0   = tile * 2048 + t * PIX;   // 8 contiguous px, same row
    const float4 tA = *reinterpret_cast<const float4*>(&tgt[p0]);
    const float4 tB = *reinterpret_cast<const float4*>(&tgt[p0 + 4]);
    float4 s0[C8];
#pragma unroll
    for (int c = 0; c < C8; ++c)
        s0[c] = *reinterpret_cast<const float4*>(&seg[c * HWPIX + p0]);

    // Same-wave LDS write; ds_read ordering via lgkmcnt only.
    wp[lane] = g0;
    wp[lane + 64] = g1;
    if (lane < CWN - 128) wp[lane + 128] = g2;

    const float cx = (float)(idx & (WW - 1));
    const float cy = (float)(idx >> 7);
    const int row  = p0 >> 7;
    const int col0 = p0 & (WW - 1);
    const float sy = ((float)row - cy) * (1.0f / 128.0f);
    float sx[PIX];
#pragma unroll
    for (int i = 0; i < PIX; ++i)
        sx[i] = ((float)(col0 + i) - cx) * (1.0f / 128.0f);

    float s_pt = 0.f, s_pp = 0.f, s_tt = 0.f;

#pragma unroll
    for (int h = 0; h < 2; ++h) {
        float f[C8][4];
        if (h == 0) {
#pragma unroll
            for (int c = 0; c < C8; ++c) {
                f[c][0] = s0[c].x; f[c][1] = s0[c].y;
                f[c][2] = s0[c].z; f[c][3] = s0[c].w;
            }
        } else {
            // second-half seg loads (issued here, overlap with half-0 tail)
#pragma unroll
            for (int c = 0; c < C8; ++c) {
                const float4 a = *reinterpret_cast<const float4*>(&seg[c * HWPIX + p0 + 4]);
                f[c][0] = a.x; f[c][1] = a.y; f[c][2] = a.z; f[c][3] = a.w;
            }
        }

        // layer 1: 10 -> 8, relu (wy*sy folded into per-o base)
        float h1[C8][4];
#pragma unroll
        for (int o = 0; o < C8; ++o) {
            const float wx = wp[o * 10 + 8];
            const float wy = wp[o * 10 + 9];
            const float base = fmaf(wy, sy, wp[80 + o]);
#pragma unroll
            for (int i = 0; i < 4; ++i) {
                float a = fmaf(wx, sx[h * 4 + i], base);
#pragma unroll
                for (int c = 0; c < C8; ++c)
                    a = fmaf(wp[o * 10 + c], f[c][i], a);
                h1[o][i] = fmaxf(a, 0.f);
            }
        }

        // layers 2+3 fused: h2 transient per output channel
        float z[4];
        {
            const float b3 = wp[168];
#pragma unroll
            for (int i = 0; i < 4; ++i) z[i] = b3;
        }
#pragma unroll
        for (int o = 0; o < C8; ++o) {
            const float bias = wp[152 + o];
            const float w3   = wp[160 + o];
#pragma unroll
            for (int i = 0; i < 4; ++i) {
                float a = bias;
#pragma unroll
                for (int c = 0; c < C8; ++c)
                    a = fmaf(wp[88 + o * 8 + c], h1[c][i], a);
                z[i] = fmaf(w3, fmaxf(a, 0.f), z[i]);
            }
        }

        // sigmoid + dice partials
        const float4 tq = (h == 0) ? tA : tB;
        const float tv[4] = {tq.x, tq.y, tq.z, tq.w};
#pragma unroll
        for (int i = 0; i < 4; ++i) {
            const float e    = __expf(-z[i]);
            const float pred = __builtin_amdgcn_rcpf(1.0f + e);
            s_pt = fmaf(pred, tv[i], s_pt);
            s_pp = fmaf(pred, pred, s_pp);
            s_tt = fmaf(tv[i], tv[i], s_tt);
        }
    }

    // wave-only reduction; lane 0 stores this wave's 3 partials.
#pragma unroll
    for (int off = 32; off > 0; off >>= 1) {
        s_pt += __shfl_down(s_pt, off);
        s_pp += __shfl_down(s_pp, off);
        s_tt += __shfl_down(s_tt, off);
    }
    if (lane == 0) { wout[0] = s_pt; wout[1] = s_pp; wout[2] = s_tt; }
}

__global__ __launch_bounds__(512) void finalize_kernel(
    const float* __restrict__ partial, float* __restrict__ out)
{
    const int t    = threadIdx.x;
    const int b    = t >> 6;   // one wave per image
    const int lane = t & 63;

    float pt = 0.f, pp = 0.f, tt = 0.f;
    const float* base = partial + b * WSLOTS_PER_B * 3;
    for (int e = lane; e < WSLOTS_PER_B; e += 64) {
        const float* q = base + e * 3;
        pt += q[0]; pp += q[1]; tt += q[2];
    }
#pragma unroll
    for (int off = 32; off > 0; off >>= 1) {
        pt += __shfl_down(pt, off);
        pp += __shfl_down(pp, off);
        tt += __shfl_down(tt, off);
    }
    __shared__ float per[BIMG];
    if (lane == 0) {
        per[b] = 1.0f - (2.0f * pt + 1.0f) / (pp + tt + 1.0f);
    }
    __syncthreads();
    if (t == 0) {
        float s = 0.f;
#pragma unroll
        for (int i = 0; i < BIMG; ++i) s += per[i];
        out[0] = s * (1.0f / (float)BIMG);
    }
}

extern "C" void kernel_launch(void* const* d_in, const int* in_sizes, int n_in,
                              void* d_out, int out_size, void* d_ws, size_t ws_size,
                              hipStream_t stream) {
    const float*     seg  = (const float*)d_in[0];
    const float*     cw   = (const float*)d_in[1];
    const int*       mask = (const int*)d_in[2];
    const long long* ind  = (const long long*)d_in[3];
    const float*     tgt  = (const float*)d_in[4];
    float* out     = (float*)d_out;
    float* partial = (float*)d_ws;   // NBLK*4*3 floats = 96 KiB

    mask_head_kernel<<<dim3(GRIDX, KOBJ, BIMG), 256, 0, stream>>>(
        seg, cw, mask, ind, tgt, partial);
    finalize_kernel<<<1, 512, 0, stream>>>(partial, out);
}